// Round 2
// baseline (765.670 us; speedup 1.0000x reference)
//
#include <hip/hip_runtime.h>
#include <hip/hip_bf16.h>

#define NN 20000
#define EE 320000
#define HD 128   // hidden

typedef _Float16 half8 __attribute__((ext_vector_type(8)));
typedef _Float16 half4 __attribute__((ext_vector_type(4)));
typedef _Float16 half2v __attribute__((ext_vector_type(2)));
typedef float floatx4 __attribute__((ext_vector_type(4)));
typedef float float2v __attribute__((ext_vector_type(2)));

// silu via HW rcp (1-ulp) instead of exact fp32 divide.
__device__ __forceinline__ float silu_f(float x){
  float e = __expf(-x);
  return x * __builtin_amdgcn_rcpf(1.f + e);
}

__device__ __forceinline__ bool ei_is64(const int* __restrict__ ei){
  return (ei[1] | ei[3] | ei[5] | ei[7]) == 0;
}
__device__ __forceinline__ int ei_src(const int* __restrict__ ei, int e, bool is64){
  return is64 ? ei[2*(size_t)e] : ei[e];
}
__device__ __forceinline__ int ei_dst(const int* __restrict__ ei, int e, bool is64){
  return is64 ? ei[2*(size_t)EE + 2*(size_t)e] : ei[EE + e];
}

__global__ __launch_bounds__(256) void sentinel_kernel(float* __restrict__ out, int n, float val){
  int i = blockIdx.x*256 + threadIdx.x;
  if (i < n) out[i] = val;
}

// ---------------- merged weight packing (w1p | w2p | dec) ----------------
__global__ __launch_bounds__(256) void pack_all_kernel(const float* __restrict__ cw1,
                                                       const float* __restrict__ cw2,
                                                       const float* __restrict__ dw1,
                                                       const float* __restrict__ dw2,
                                                       _Float16* __restrict__ w1p,
                                                       _Float16* __restrict__ w2p,
                                                       _Float16* __restrict__ w1dp,
                                                       _Float16* __restrict__ w2dp){
  int idx = blockIdx.x*256 + threadIdx.x;   // 1248 blocks = 319488 exact
  if (idx < 196608){
    int j   = idx & 7;
    int ln  = (idx >> 3) & 63;
    int rest= idx >> 9;
    int cb  = rest & 15;
    int rest2 = rest >> 4;
    int ks  = rest2 & 3;
    int l   = rest2 >> 2;
    int k = ks*32 + (ln>>4)*8 + j;
    int c = cb*16 + (ln&15);
    float v = (c < 128) ? cw1[(size_t)l*33152 + (size_t)k*128 + c]
                        : cw1[(size_t)l*33152 + (size_t)(128+k)*128 + (c-128)];
    w1p[idx] = (_Float16)v;
  } else if (idx < 294912){
    int t = idx - 196608;
    int j   = t & 7;
    int ln  = (t >> 3) & 63;
    int rest= t >> 9;
    int cb  = rest & 7;
    int rest2 = rest >> 3;
    int ks  = rest2 & 3;
    int l   = rest2 >> 2;
    int k = ks*32 + (ln>>4)*8 + j;
    int c = cb*16 + (ln&15);
    w2p[t] = (_Float16)cw2[(size_t)l*16384 + (size_t)k*128 + c];
  } else {
    int t2 = idx - 294912;
    if (t2 < 16384){
      int j = t2 & 7, ln = (t2>>3)&63, cb = (t2>>9)&7, ks = t2>>12;
      int k = ks*32 + (ln>>4)*8 + j;
      int c = cb*16 + (ln&15);
      w1dp[t2] = (_Float16)dw1[(size_t)k*128 + c];
    } else {
      int t = t2 - 16384;
      int j = t & 7, ln = (t>>3)&63, cb = (t>>9)&3, ks = t>>11;
      int k = ks*32 + (ln>>4)*8 + j;
      int c = cb*16 + (ln&15);
      w2dp[t] = (_Float16)dw2[(size_t)k*64 + c];
    }
  }
}

// ---------------- CSR build ----------------
__global__ __launch_bounds__(256) void count_kernel(const int* __restrict__ ei, int* __restrict__ cnt){
  int e = blockIdx.x*256 + threadIdx.x;   // EE/256 exact
  bool is64 = ei_is64(ei);
  atomicAdd(&cnt[ei_dst(ei, e, is64)], 1);
}

__global__ __launch_bounds__(1024) void scan_kernel(int* __restrict__ cntcur,
                                                    int* __restrict__ row_start,
                                                    float* __restrict__ invd){
  __shared__ int part[1024];
  const int t = threadIdx.x;
  const int base = t*20;
  int loc[20];
  int sum = 0;
  #pragma unroll
  for (int i=0;i<20;++i){
    int n = base+i;
    int v = (n < NN) ? cntcur[n] : 0;
    loc[i] = sum; sum += v;
  }
  part[t] = sum;
  __syncthreads();
  for (int off=1; off<1024; off<<=1){
    int v = (t >= off) ? part[t-off] : 0;
    __syncthreads();
    part[t] += v;
    __syncthreads();
  }
  int pre = (t > 0) ? part[t-1] : 0;
  #pragma unroll
  for (int i=0;i<20;++i){
    int n = base+i;
    if (n < NN){
      int rs = pre + loc[i];
      int deg = ((i<19)?loc[i+1]:sum) - loc[i];
      row_start[n] = rs;
      invd[n] = (deg > 0) ? 1.f/(float)deg : 0.f;
      cntcur[n] = rs;
    }
  }
  if (t == 1023) row_start[NN] = part[1023];
}

// scatter: one 16B record per edge: {ea0,ea1,ea2 (fp32 bits), src*256}.
__global__ __launch_bounds__(256) void scatter_kernel(const int* __restrict__ ei,
                                                      const float* __restrict__ eattr,
                                                      int* __restrict__ cur,
                                                      int4* __restrict__ rec){
  int e = blockIdx.x*256 + threadIdx.x;   // EE/256 exact
  bool is64 = ei_is64(ei);
  int s = ei_src(ei, e, is64);
  int d = ei_dst(ei, e, is64);
  int pos = atomicAdd(&cur[d], 1);
  int4 r;
  r.x = __float_as_int(eattr[(size_t)e*3+0]);
  r.y = __float_as_int(eattr[(size_t)e*3+1]);
  r.z = __float_as_int(eattr[(size_t)e*3+2]);
  r.w = s*256;   // pre-scaled UV row element-offset
  rec[pos] = r;
}

// ---------------- encoder: x(N,14) -> h(N,128) fp32 + hh fp16 ----------------
__global__ __launch_bounds__(128) void encoder_kernel(
    const float* __restrict__ x, const float* __restrict__ w1, const float* __restrict__ b1,
    const float* __restrict__ w2, const float* __restrict__ b2,
    float* __restrict__ h, _Float16* __restrict__ hh)
{
  __shared__ float xs[16][14];
  __shared__ float s1[16][128];
  const int n0 = blockIdx.x*16;
  const int tid = threadIdx.x;
  for (int idx=tid; idx<224; idx+=128){
    int i = idx/14, k = idx%14;
    xs[i][k] = x[(size_t)(n0+i)*14 + k];
  }
  __syncthreads();
  const int o = tid;
  float acc[16];
  float bv = b1[o];
  #pragma unroll
  for (int i=0;i<16;++i) acc[i] = bv;
  for (int k=0;k<14;++k){
    float w = w1[k*128+o];
    #pragma unroll
    for (int i=0;i<16;++i) acc[i] += xs[i][k]*w;
  }
  #pragma unroll
  for (int i=0;i<16;++i) s1[i][o] = silu_f(acc[i]);
  __syncthreads();
  float bv2 = b2[o];
  #pragma unroll
  for (int i=0;i<16;++i) acc[i] = bv2;
  for (int k=0;k<128;k+=4){
    float w0=w2[(k+0)*128+o], w1v=w2[(k+1)*128+o], w2v=w2[(k+2)*128+o], w3v=w2[(k+3)*128+o];
    #pragma unroll
    for (int i=0;i<16;++i){
      float4 sv = *(const float4*)&s1[i][k];
      acc[i] += sv.x*w0 + sv.y*w1v + sv.z*w2v + sv.w*w3v;
    }
  }
  #pragma unroll
  for (int i=0;i<16;++i){
    size_t off = (size_t)(n0+i)*HD + o;
    h[off] = acc[i];
    hh[off] = (_Float16)acc[i];
  }
}

// ---------------- proj (MFMA, layer 0 only): UV = [hh·W1d + b1 | hh·W1s] ----------------
__global__ __launch_bounds__(256) void proj_kernel(
    const _Float16* __restrict__ hh, const _Float16* __restrict__ w1p,
    const float* __restrict__ b1, _Float16* __restrict__ UV)
{
  const int tid = threadIdx.x;
  const int wv  = tid >> 6;
  const int ln  = tid & 63;
  const int q   = ln >> 4;
  const int m   = ln & 15;
  const int n0  = (blockIdx.x*4 + wv)*16;
  if (n0 >= NN) return;

  floatx4 acc[16];
  #pragma unroll
  for (int cb=0;cb<16;++cb) acc[cb] = (floatx4){0.f,0.f,0.f,0.f};

  #pragma unroll
  for (int ks=0; ks<4; ++ks){
    half8 a = *(const half8*)(hh + (size_t)(n0+m)*HD + ks*32 + q*8);
    const _Float16* wb = w1p + (size_t)(ks*16*64 + ln)*8;
    #pragma unroll
    for (int cb=0; cb<16; ++cb){
      half8 b = *(const half8*)(wb + (size_t)cb*512);
      acc[cb] = __builtin_amdgcn_mfma_f32_16x16x32_f16(a, b, acc[cb], 0,0,0);
    }
  }
  #pragma unroll
  for (int cb=0; cb<16; ++cb){
    const int c = cb*16 + m;
    const float bias = (c < 128) ? b1[c] : 0.f;
    #pragma unroll
    for (int r=0;r<4;++r)
      UV[(size_t)(n0+q*4+r)*256 + c] = (_Float16)(acc[cb][r] + bias);
  }
}

// ---------------- fused layer: edge_agg (LDS) + node matmul + next proj ----------------
// Block = 16 nodes, 4 waves. Phase 1: each wave aggregates 4 nodes' edges into
// LDS S (no HBM round-trip). Phase 2: the two MFMA matmuls split column-blocks
// across the 4 waves. UV is double-buffered (read cur / write next) so the
// whole layer is one launch: 1250 blocks (~19.5 waves/CU) instead of
// 5000-blk edge kernel + 313-blk (1.2 wave/SIMD) MFMA kernel.
__global__ __launch_bounds__(256) void layer_kernel(
    const _Float16* __restrict__ UVc, _Float16* __restrict__ UVn,
    const int* __restrict__ row_start, const int4* __restrict__ rec,
    const float* __restrict__ w1e, const float* __restrict__ invd,
    const _Float16* __restrict__ w2p, const float* __restrict__ b2,
    float* __restrict__ h, _Float16* __restrict__ hh,
    const _Float16* __restrict__ w1pn, const float* __restrict__ b1n,
    int do_proj)
{
  __shared__ _Float16 Sl[16][136];
  __shared__ _Float16 hl[16][136];
  const int tid = threadIdx.x;
  const int wv  = tid >> 6;
  const int ln  = tid & 63;
  const int q   = ln >> 4;
  const int m   = ln & 15;
  const int n0  = blockIdx.x * 16;     // grid = NN/16 = 1250 exact
  const int c0  = ln*2;

  // ---- phase 1: edge aggregation, 4 nodes per wave ----
  const float2v wc0 = *(const float2v*)(w1e +   0 + c0);
  const float2v wc1 = *(const float2v*)(w1e + 128 + c0);
  const float2v wc2 = *(const float2v*)(w1e + 256 + c0);
  #pragma unroll
  for (int i=0;i<4;++i){
    const int n = n0 + wv*4 + i;
    half2v uvp = *(const half2v*)(UVc + (size_t)n*256 + c0);
    float2v u; u[0] = (float)uvp[0]; u[1] = (float)uvp[1];
    const int rs = row_start[n], re = row_start[n+1];
    float2v a = {0.f, 0.f};
    if (re > rs){
      int4 r = rec[rs];
      half2v v = *(const half2v*)(UVc + (size_t)r.w + 128 + c0);
      for (int e = rs+1; e <= re; ++e){
        int4 r2 = {0,0,0,0};
        half2v v2 = {};
        if (e < re){
          r2 = rec[e];
          v2 = *(const half2v*)(UVc + (size_t)r2.w + 128 + c0);
        }
        float2v p = u;
        p += __int_as_float(r.x) * wc0;
        p += __int_as_float(r.y) * wc1;
        p += __int_as_float(r.z) * wc2;
        p[0] += (float)v[0];
        p[1] += (float)v[1];
        a[0] += silu_f(p[0]);
        a[1] += silu_f(p[1]);
        r = r2; v = v2;
      }
    }
    const float iv = invd[n];
    half2v outv; outv[0] = (_Float16)(a[0]*iv); outv[1] = (_Float16)(a[1]*iv);
    *(half2v*)&Sl[wv*4+i][c0] = outv;
  }
  __syncthreads();

  // ---- phase 2: h += S·W2 + gate·b2 (2 col-blocks per wave) ----
  floatx4 acc[2];
  acc[0] = (floatx4){0.f,0.f,0.f,0.f};
  acc[1] = (floatx4){0.f,0.f,0.f,0.f};
  #pragma unroll
  for (int ks=0; ks<4; ++ks){
    half8 a = *(const half8*)&Sl[m][ks*32 + q*8];
    const _Float16* wb = w2p + (size_t)(ks*8*64 + ln)*8;
    #pragma unroll
    for (int j=0;j<2;++j){
      half8 b = *(const half8*)(wb + (size_t)(wv*2+j)*512);
      acc[j] = __builtin_amdgcn_mfma_f32_16x16x32_f16(a, b, acc[j], 0,0,0);
    }
  }
  float gate[4];
  #pragma unroll
  for (int r=0;r<4;++r) gate[r] = (invd[n0 + q*4 + r] > 0.f) ? 1.f : 0.f;
  #pragma unroll
  for (int j=0; j<2; ++j){
    const int c = (wv*2+j)*16 + m;
    const float bv = b2[c];
    #pragma unroll
    for (int r=0;r<4;++r){
      size_t off = (size_t)(n0+q*4+r)*HD + c;
      float hv = h[off] + acc[j][r] + gate[r]*bv;
      h[off] = hv;
      hh[off] = (_Float16)hv;
      hl[q*4+r][c] = (_Float16)hv;
    }
  }
  __syncthreads();

  // ---- phase 3: fused proj of next layer (4 col-blocks per wave) ----
  if (do_proj){
    floatx4 acc2[4];
    #pragma unroll
    for (int j=0;j<4;++j) acc2[j] = (floatx4){0.f,0.f,0.f,0.f};
    #pragma unroll
    for (int ks=0; ks<4; ++ks){
      half8 a = *(const half8*)&hl[m][ks*32 + q*8];
      const _Float16* wb = w1pn + (size_t)(ks*16*64 + ln)*8;
      #pragma unroll
      for (int j=0; j<4; ++j){
        half8 b = *(const half8*)(wb + (size_t)(wv*4+j)*512);
        acc2[j] = __builtin_amdgcn_mfma_f32_16x16x32_f16(a, b, acc2[j], 0,0,0);
      }
    }
    #pragma unroll
    for (int j=0; j<4; ++j){
      const int c = (wv*4+j)*16 + m;
      const float bias = (c < 128) ? b1n[c] : 0.f;
      #pragma unroll
      for (int r=0;r<4;++r)
        UVn[(size_t)(n0+q*4+r)*256 + c] = (_Float16)(acc2[j][r] + bias);
    }
  }
}

// ---------------- decoder (MFMA stages 1-2): hh -> out(N,9) ----------------
__global__ __launch_bounds__(256) void decoder_kernel(
    const _Float16* __restrict__ hh,
    const _Float16* __restrict__ w1dp, const float* __restrict__ db1,
    const _Float16* __restrict__ w2dp, const float* __restrict__ db2,
    const float* __restrict__ dw3, const float* __restrict__ db3,
    float* __restrict__ out)
{
  __shared__ _Float16 d1[4][16][136];
  __shared__ float s2m[4][16][66];
  const int tid = threadIdx.x;
  const int wv  = tid >> 6;
  const int ln  = tid & 63;
  const int q   = ln >> 4;
  const int m   = ln & 15;
  int g = blockIdx.x*4 + wv;
  if (g > 1249) g = 1249;         // dup waves recompute same group; out writes identical
  const int n0 = g*16;

  floatx4 acc1[8];
  #pragma unroll
  for (int cb=0;cb<8;++cb) acc1[cb] = (floatx4){0.f,0.f,0.f,0.f};
  #pragma unroll
  for (int ks=0; ks<4; ++ks){
    half8 a = *(const half8*)(hh + (size_t)(n0+m)*HD + ks*32 + q*8);
    const _Float16* wb = w1dp + (size_t)(ks*8*64 + ln)*8;
    #pragma unroll
    for (int cb=0; cb<8; ++cb){
      half8 b = *(const half8*)(wb + (size_t)cb*512);
      acc1[cb] = __builtin_amdgcn_mfma_f32_16x16x32_f16(a, b, acc1[cb], 0,0,0);
    }
  }
  #pragma unroll
  for (int cb=0; cb<8; ++cb){
    const int c = cb*16 + m;
    const float bv = db1[c];
    #pragma unroll
    for (int r=0;r<4;++r)
      d1[wv][q*4+r][c] = (_Float16)silu_f(acc1[cb][r] + bv);
  }
  __syncthreads();
  floatx4 acc2[4];
  #pragma unroll
  for (int cb=0;cb<4;++cb) acc2[cb] = (floatx4){0.f,0.f,0.f,0.f};
  #pragma unroll
  for (int ks=0; ks<4; ++ks){
    half8 a = *(const half8*)&d1[wv][m][ks*32 + q*8];
    const _Float16* wb = w2dp + (size_t)(ks*4*64 + ln)*8;
    #pragma unroll
    for (int cb=0; cb<4; ++cb){
      half8 b = *(const half8*)(wb + (size_t)cb*512);
      acc2[cb] = __builtin_amdgcn_mfma_f32_16x16x32_f16(a, b, acc2[cb], 0,0,0);
    }
  }
  #pragma unroll
  for (int cb=0; cb<4; ++cb){
    const int c = cb*16 + m;
    const float bv = db2[c];
    #pragma unroll
    for (int r=0;r<4;++r)
      s2m[wv][q*4+r][c] = silu_f(acc2[cb][r] + bv);
  }
  __syncthreads();
  for (int idx = ln; idx < 144; idx += 64){
    int i = idx/9, oo = idx%9;
    float a = db3[oo];
    #pragma unroll 8
    for (int k=0;k<64;++k) a += s2m[wv][i][k]*dw3[k*9+oo];
    out[(size_t)(n0+i)*9 + oo] = a;
  }
}

// ---------------- workspace layout (41,839,040 B) ----------------
constexpr size_t OFF_H    = 0;                         // 10,240,000
constexpr size_t OFF_HH   = 10240000;                  //  5,120,000
constexpr size_t OFF_UVA  = 15360000;                  // 10,240,000
constexpr size_t OFF_UVB  = 25600000;                  // 10,240,000
constexpr size_t OFF_INVD = 35840000;                  //     80,000
constexpr size_t OFF_RS   = 35920000;                  //     80,064
constexpr size_t OFF_CUR  = 36000064;                  //     80,000
constexpr size_t OFF_REC  = 36080064;                  //  5,120,000 (int4/edge)
constexpr size_t OFF_W1P  = 41200064;                  //    393,216
constexpr size_t OFF_W2P  = 41593280;                  //    196,608
constexpr size_t OFF_DW1P = 41789888;                  //     32,768
constexpr size_t OFF_DW2P = 41822656;                  //     16,384
constexpr size_t WS_NEEDED= 41839040;

extern "C" void kernel_launch(void* const* d_in, const int* in_sizes, int n_in,
                              void* d_out, int out_size, void* d_ws, size_t ws_size,
                              hipStream_t stream)
{
  float* out = (float*)d_out;
  const int nout_blk = (out_size + 255)/256;

  static const int EXP_SIZES[17] = {280000,640000,960000,1792,128,16384,128,
                                    198912,768,98304,768,16384,128,8192,64,576,9};
  if (n_in != 17){
    sentinel_kernel<<<nout_blk, 256, 0, stream>>>(out, out_size, 2.0e7f + (float)n_in*1.0e3f);
    return;
  }
  for (int i = 0; i < 17; ++i){
    if (in_sizes[i] != EXP_SIZES[i]){
      int sz = in_sizes[i] < 99999 ? in_sizes[i] : 99999;
      sentinel_kernel<<<nout_blk, 256, 0, stream>>>(out, out_size,
          1.0e7f + (float)i*1.0e5f + (float)sz);
      return;
    }
  }
  if (ws_size < WS_NEEDED){
    sentinel_kernel<<<nout_blk, 256, 0, stream>>>(out, out_size, 1.0e6f);
    return;
  }

  const float* x       = (const float*)d_in[0];
  const int*   ei      = (const int*)  d_in[1];
  const float* eattr   = (const float*)d_in[2];
  const float* enc_w1  = (const float*)d_in[3];
  const float* enc_b1  = (const float*)d_in[4];
  const float* enc_w2  = (const float*)d_in[5];
  const float* enc_b2  = (const float*)d_in[6];
  const float* conv_w1 = (const float*)d_in[7];
  const float* conv_b1 = (const float*)d_in[8];
  const float* conv_w2 = (const float*)d_in[9];
  const float* conv_b2 = (const float*)d_in[10];
  const float* dec_w1  = (const float*)d_in[11];
  const float* dec_b1  = (const float*)d_in[12];
  const float* dec_w2  = (const float*)d_in[13];
  const float* dec_b2  = (const float*)d_in[14];
  const float* dec_w3  = (const float*)d_in[15];
  const float* dec_b3  = (const float*)d_in[16];

  char* ws = (char*)d_ws;
  float*    h     = (float*)   (ws + OFF_H);
  _Float16* hh    = (_Float16*)(ws + OFF_HH);
  _Float16* UVa   = (_Float16*)(ws + OFF_UVA);
  _Float16* UVb   = (_Float16*)(ws + OFF_UVB);
  float*    invd  = (float*)   (ws + OFF_INVD);
  int*      rstart= (int*)     (ws + OFF_RS);
  int*      cur   = (int*)     (ws + OFF_CUR);
  int4*     rec   = (int4*)    (ws + OFF_REC);
  _Float16* w1p   = (_Float16*)(ws + OFF_W1P);
  _Float16* w2p   = (_Float16*)(ws + OFF_W2P);
  _Float16* w1dp  = (_Float16*)(ws + OFF_DW1P);
  _Float16* w2dp  = (_Float16*)(ws + OFF_DW2P);

  hipMemsetAsync(cur, 0, (size_t)NN*sizeof(int), stream);

  pack_all_kernel<<<1248, 256, 0, stream>>>(conv_w1, conv_w2, dec_w1, dec_w2,
                                            w1p, w2p, w1dp, w2dp);
  count_kernel<<<EE/256, 256, 0, stream>>>(ei, cur);
  scan_kernel<<<1, 1024, 0, stream>>>(cur, rstart, invd);
  scatter_kernel<<<EE/256, 256, 0, stream>>>(ei, eattr, cur, rec);
  encoder_kernel<<<NN/16, 128, 0, stream>>>(x, enc_w1, enc_b1, enc_w2, enc_b2, h, hh);
  proj_kernel<<<313, 256, 0, stream>>>(hh, w1p, conv_b1, UVa);   // layer 0 proj -> UVa
  for (int l=0; l<6; ++l){
    _Float16* UVc = (l & 1) ? UVb : UVa;
    _Float16* UVn = (l & 1) ? UVa : UVb;
    const int lp = (l < 5) ? l+1 : 0;   // dummy valid ptrs for last layer
    layer_kernel<<<NN/16, 256, 0, stream>>>(UVc, UVn, rstart, rec,
                                            conv_w1 + (size_t)l*33152 + 32768,
                                            invd,
                                            w2p + (size_t)l*16384,
                                            conv_b2 + (size_t)l*128,
                                            h, hh,
                                            w1p + (size_t)lp*32768,
                                            conv_b1 + (size_t)lp*128,
                                            (l < 5) ? 1 : 0);
  }
  decoder_kernel<<<313, 256, 0, stream>>>(hh, w1dp, dec_b1, w2dp, dec_b2,
                                          dec_w3, dec_b3, out);
}

// Round 3
// 472.103 us; speedup vs baseline: 1.6218x; 1.6218x over previous
//
#include <hip/hip_runtime.h>
#include <hip/hip_bf16.h>

#define NN 20000
#define EE 320000
#define HD 128   // hidden

typedef _Float16 half8 __attribute__((ext_vector_type(8)));
typedef _Float16 half4 __attribute__((ext_vector_type(4)));
typedef _Float16 half2v __attribute__((ext_vector_type(2)));
typedef float floatx4 __attribute__((ext_vector_type(4)));
typedef float float2v __attribute__((ext_vector_type(2)));

// silu via HW rcp (1-ulp) instead of exact fp32 divide.
__device__ __forceinline__ float silu_f(float x){
  float e = __expf(-x);
  return x * __builtin_amdgcn_rcpf(1.f + e);
}

__device__ __forceinline__ bool ei_is64(const int* __restrict__ ei){
  return (ei[1] | ei[3] | ei[5] | ei[7]) == 0;
}
__device__ __forceinline__ int ei_src(const int* __restrict__ ei, int e, bool is64){
  return is64 ? ei[2*(size_t)e] : ei[e];
}
__device__ __forceinline__ int ei_dst(const int* __restrict__ ei, int e, bool is64){
  return is64 ? ei[2*(size_t)EE + 2*(size_t)e] : ei[EE + e];
}

__global__ __launch_bounds__(256) void sentinel_kernel(float* __restrict__ out, int n, float val){
  int i = blockIdx.x*256 + threadIdx.x;
  if (i < n) out[i] = val;
}

// ---------------- merged weight packing (w1p | w2p | dec) ----------------
__global__ __launch_bounds__(256) void pack_all_kernel(const float* __restrict__ cw1,
                                                       const float* __restrict__ cw2,
                                                       const float* __restrict__ dw1,
                                                       const float* __restrict__ dw2,
                                                       _Float16* __restrict__ w1p,
                                                       _Float16* __restrict__ w2p,
                                                       _Float16* __restrict__ w1dp,
                                                       _Float16* __restrict__ w2dp){
  int idx = blockIdx.x*256 + threadIdx.x;   // 1248 blocks = 319488 exact
  if (idx < 196608){
    int j   = idx & 7;
    int ln  = (idx >> 3) & 63;
    int rest= idx >> 9;
    int cb  = rest & 15;
    int rest2 = rest >> 4;
    int ks  = rest2 & 3;
    int l   = rest2 >> 2;
    int k = ks*32 + (ln>>4)*8 + j;
    int c = cb*16 + (ln&15);
    float v = (c < 128) ? cw1[(size_t)l*33152 + (size_t)k*128 + c]
                        : cw1[(size_t)l*33152 + (size_t)(128+k)*128 + (c-128)];
    w1p[idx] = (_Float16)v;
  } else if (idx < 294912){
    int t = idx - 196608;
    int j   = t & 7;
    int ln  = (t >> 3) & 63;
    int rest= t >> 9;
    int cb  = rest & 7;
    int rest2 = rest >> 3;
    int ks  = rest2 & 3;
    int l   = rest2 >> 2;
    int k = ks*32 + (ln>>4)*8 + j;
    int c = cb*16 + (ln&15);
    w2p[t] = (_Float16)cw2[(size_t)l*16384 + (size_t)k*128 + c];
  } else {
    int t2 = idx - 294912;
    if (t2 < 16384){
      int j = t2 & 7, ln = (t2>>3)&63, cb = (t2>>9)&7, ks = t2>>12;
      int k = ks*32 + (ln>>4)*8 + j;
      int c = cb*16 + (ln&15);
      w1dp[t2] = (_Float16)dw1[(size_t)k*128 + c];
    } else {
      int t = t2 - 16384;
      int j = t & 7, ln = (t>>3)&63, cb = (t>>9)&3, ks = t>>11;
      int k = ks*32 + (ln>>4)*8 + j;
      int c = cb*16 + (ln&15);
      w2dp[t] = (_Float16)dw2[(size_t)k*64 + c];
    }
  }
}

// ---------------- CSR build ----------------
__global__ __launch_bounds__(256) void count_kernel(const int* __restrict__ ei, int* __restrict__ cnt){
  int e = blockIdx.x*256 + threadIdx.x;   // EE/256 exact
  bool is64 = ei_is64(ei);
  atomicAdd(&cnt[ei_dst(ei, e, is64)], 1);
}

__global__ __launch_bounds__(1024) void scan_kernel(int* __restrict__ cntcur,
                                                    int* __restrict__ row_start,
                                                    float* __restrict__ invd){
  __shared__ int part[1024];
  const int t = threadIdx.x;
  const int base = t*20;
  int loc[20];
  int sum = 0;
  #pragma unroll
  for (int i=0;i<20;++i){
    int n = base+i;
    int v = (n < NN) ? cntcur[n] : 0;
    loc[i] = sum; sum += v;
  }
  part[t] = sum;
  __syncthreads();
  for (int off=1; off<1024; off<<=1){
    int v = (t >= off) ? part[t-off] : 0;
    __syncthreads();
    part[t] += v;
    __syncthreads();
  }
  int pre = (t > 0) ? part[t-1] : 0;
  #pragma unroll
  for (int i=0;i<20;++i){
    int n = base+i;
    if (n < NN){
      int rs = pre + loc[i];
      int deg = ((i<19)?loc[i+1]:sum) - loc[i];
      row_start[n] = rs;
      invd[n] = (deg > 0) ? 1.f/(float)deg : 0.f;
      cntcur[n] = rs;
    }
  }
  if (t == 1023) row_start[NN] = part[1023];
}

// scatter: one 16B record per edge: {ea0,ea1,ea2 (fp32 bits), src*256}.
__global__ __launch_bounds__(256) void scatter_kernel(const int* __restrict__ ei,
                                                      const float* __restrict__ eattr,
                                                      int* __restrict__ cur,
                                                      int4* __restrict__ rec){
  int e = blockIdx.x*256 + threadIdx.x;   // EE/256 exact
  bool is64 = ei_is64(ei);
  int s = ei_src(ei, e, is64);
  int d = ei_dst(ei, e, is64);
  int pos = atomicAdd(&cur[d], 1);
  int4 r;
  r.x = __float_as_int(eattr[(size_t)e*3+0]);
  r.y = __float_as_int(eattr[(size_t)e*3+1]);
  r.z = __float_as_int(eattr[(size_t)e*3+2]);
  r.w = s*256;   // pre-scaled UV row element-offset
  rec[pos] = r;
}

// ---------------- encoder: x(N,14) -> h(N,128) fp32 + hh fp16 ----------------
__global__ __launch_bounds__(128) void encoder_kernel(
    const float* __restrict__ x, const float* __restrict__ w1, const float* __restrict__ b1,
    const float* __restrict__ w2, const float* __restrict__ b2,
    float* __restrict__ h, _Float16* __restrict__ hh)
{
  __shared__ float xs[16][14];
  __shared__ float s1[16][128];
  const int n0 = blockIdx.x*16;
  const int tid = threadIdx.x;
  for (int idx=tid; idx<224; idx+=128){
    int i = idx/14, k = idx%14;
    xs[i][k] = x[(size_t)(n0+i)*14 + k];
  }
  __syncthreads();
  const int o = tid;
  float acc[16];
  float bv = b1[o];
  #pragma unroll
  for (int i=0;i<16;++i) acc[i] = bv;
  for (int k=0;k<14;++k){
    float w = w1[k*128+o];
    #pragma unroll
    for (int i=0;i<16;++i) acc[i] += xs[i][k]*w;
  }
  #pragma unroll
  for (int i=0;i<16;++i) s1[i][o] = silu_f(acc[i]);
  __syncthreads();
  float bv2 = b2[o];
  #pragma unroll
  for (int i=0;i<16;++i) acc[i] = bv2;
  for (int k=0;k<128;k+=4){
    float w0=w2[(k+0)*128+o], w1v=w2[(k+1)*128+o], w2v=w2[(k+2)*128+o], w3v=w2[(k+3)*128+o];
    #pragma unroll
    for (int i=0;i<16;++i){
      float4 sv = *(const float4*)&s1[i][k];
      acc[i] += sv.x*w0 + sv.y*w1v + sv.z*w2v + sv.w*w3v;
    }
  }
  #pragma unroll
  for (int i=0;i<16;++i){
    size_t off = (size_t)(n0+i)*HD + o;
    h[off] = acc[i];
    hh[off] = (_Float16)acc[i];
  }
}

// ---------------- proj (1250 blocks, 4 cb/wave): UV = [hh·W1d + b1 | hh·W1s] ----------------
// r2 re-grid: 313 blocks (1.2 waves/SIMD, latency-exposed) -> 1250 blocks with
// column-blocks split across the 4 waves (the structure that was cheap in the
// fused layer_kernel's MFMA phases).
__global__ __launch_bounds__(256) void proj_kernel(
    const _Float16* __restrict__ hh, const _Float16* __restrict__ w1p,
    const float* __restrict__ b1, _Float16* __restrict__ UV)
{
  const int tid = threadIdx.x;
  const int wv  = tid >> 6;
  const int ln  = tid & 63;
  const int q   = ln >> 4;
  const int m   = ln & 15;
  const int n0  = blockIdx.x*16;      // grid = NN/16 = 1250 exact

  floatx4 acc[4];
  #pragma unroll
  for (int j=0;j<4;++j) acc[j] = (floatx4){0.f,0.f,0.f,0.f};

  #pragma unroll
  for (int ks=0; ks<4; ++ks){
    half8 a = *(const half8*)(hh + (size_t)(n0+m)*HD + ks*32 + q*8);
    const _Float16* wb = w1p + (size_t)(ks*16*64 + ln)*8;
    #pragma unroll
    for (int j=0; j<4; ++j){
      half8 b = *(const half8*)(wb + (size_t)(wv*4+j)*512);
      acc[j] = __builtin_amdgcn_mfma_f32_16x16x32_f16(a, b, acc[j], 0,0,0);
    }
  }
  #pragma unroll
  for (int j=0; j<4; ++j){
    const int c = (wv*4+j)*16 + m;
    const float bias = (c < 128) ? b1[c] : 0.f;
    #pragma unroll
    for (int r=0;r<4;++r)
      UV[(size_t)(n0+q*4+r)*256 + c] = (_Float16)(acc[j][r] + bias);
  }
}

// ---------------- edge_agg: per-node mean of silu(U+V[src]+ea·We) ----------------
// r1 version, untouched (best known): 5000 blocks, one node per wave.
__global__ __launch_bounds__(256) void edge_agg_kernel(
    const _Float16* __restrict__ UV, const int* __restrict__ row_start,
    const int4* __restrict__ rec,
    const float* __restrict__ w1e, const float* __restrict__ invd,
    _Float16* __restrict__ S)
{
  const int tid = threadIdx.x;
  const int wv  = __builtin_amdgcn_readfirstlane(tid >> 6);
  const int ln  = tid & 63;
  const int n   = blockIdx.x*4 + wv;   // grid NN/4 = 5000 exact
  const int c0  = ln*2;

  const float2v wc0 = *(const float2v*)(w1e +   0 + c0);
  const float2v wc1 = *(const float2v*)(w1e + 128 + c0);
  const float2v wc2 = *(const float2v*)(w1e + 256 + c0);

  half2v uvp = *(const half2v*)(UV + (size_t)n*256 + c0);
  float2v u; u[0] = (float)uvp[0]; u[1] = (float)uvp[1];

  const int rs = row_start[n], re = row_start[n+1];
  float2v a = {0.f, 0.f};
  if (re > rs){
    int4 r = rec[rs];
    half2v v = *(const half2v*)(UV + (size_t)r.w + 128 + c0);
    for (int e = rs+1; e <= re; ++e){
      int4 r2 = {0,0,0,0};
      half2v v2 = {};
      if (e < re){
        r2 = rec[e];
        v2 = *(const half2v*)(UV + (size_t)r2.w + 128 + c0);
      }
      float2v p = u;
      p += __int_as_float(r.x) * wc0;
      p += __int_as_float(r.y) * wc1;
      p += __int_as_float(r.z) * wc2;
      p[0] += (float)v[0];
      p[1] += (float)v[1];
      a[0] += silu_f(p[0]);
      a[1] += silu_f(p[1]);
      r = r2; v = v2;
    }
  }
  const float iv = invd[n];
  half2v outv; outv[0] = (_Float16)(a[0]*iv); outv[1] = (_Float16)(a[1]*iv);
  *(half2v*)(S + (size_t)n*HD + c0) = outv;
}

// ---------------- node_proj (1250 blocks): h += S·W2 + gate·b2 ; hh ; fused proj(l+1) ----------------
// Column-blocks split across 4 waves: node matmul 2 cb/wave, proj 4 cb/wave.
__global__ __launch_bounds__(256) void node_proj_kernel(
    const _Float16* __restrict__ S, const _Float16* __restrict__ w2p,
    const float* __restrict__ b2, const float* __restrict__ invd,
    float* __restrict__ h, _Float16* __restrict__ hh,
    const _Float16* __restrict__ w1pn, const float* __restrict__ b1n,
    _Float16* __restrict__ UV, int do_proj)
{
  __shared__ _Float16 hl[16][136];
  const int tid = threadIdx.x;
  const int wv  = tid >> 6;
  const int ln  = tid & 63;
  const int q   = ln >> 4;
  const int m   = ln & 15;
  const int n0  = blockIdx.x*16;      // grid = NN/16 = 1250 exact

  floatx4 acc[2];
  acc[0] = (floatx4){0.f,0.f,0.f,0.f};
  acc[1] = (floatx4){0.f,0.f,0.f,0.f};
  #pragma unroll
  for (int ks=0; ks<4; ++ks){
    half8 a = *(const half8*)(S + (size_t)(n0+m)*HD + ks*32 + q*8);
    const _Float16* wb = w2p + (size_t)(ks*8*64 + ln)*8;
    #pragma unroll
    for (int j=0;j<2;++j){
      half8 b = *(const half8*)(wb + (size_t)(wv*2+j)*512);
      acc[j] = __builtin_amdgcn_mfma_f32_16x16x32_f16(a, b, acc[j], 0,0,0);
    }
  }
  float gate[4];
  #pragma unroll
  for (int r=0;r<4;++r) gate[r] = (invd[n0 + q*4 + r] > 0.f) ? 1.f : 0.f;
  #pragma unroll
  for (int j=0; j<2; ++j){
    const int c = (wv*2+j)*16 + m;
    const float bv = b2[c];
    #pragma unroll
    for (int r=0;r<4;++r){
      size_t off = (size_t)(n0+q*4+r)*HD + c;
      float hv = h[off] + acc[j][r] + gate[r]*bv;
      h[off] = hv;
      hh[off] = (_Float16)hv;
      hl[q*4+r][c] = (_Float16)hv;
    }
  }
  __syncthreads();
  if (do_proj){
    floatx4 acc2[4];
    #pragma unroll
    for (int j=0;j<4;++j) acc2[j] = (floatx4){0.f,0.f,0.f,0.f};
    #pragma unroll
    for (int ks=0; ks<4; ++ks){
      half8 a = *(const half8*)&hl[m][ks*32 + q*8];
      const _Float16* wb = w1pn + (size_t)(ks*16*64 + ln)*8;
      #pragma unroll
      for (int j=0; j<4; ++j){
        half8 b = *(const half8*)(wb + (size_t)(wv*4+j)*512);
        acc2[j] = __builtin_amdgcn_mfma_f32_16x16x32_f16(a, b, acc2[j], 0,0,0);
      }
    }
    #pragma unroll
    for (int j=0; j<4; ++j){
      const int c = (wv*4+j)*16 + m;
      const float bias = (c < 128) ? b1n[c] : 0.f;
      #pragma unroll
      for (int r=0;r<4;++r)
        UV[(size_t)(n0+q*4+r)*256 + c] = (_Float16)(acc2[j][r] + bias);
    }
  }
}

// ---------------- decoder (1250 blocks): hh -> out(N,9) ----------------
__global__ __launch_bounds__(256) void decoder_kernel(
    const _Float16* __restrict__ hh,
    const _Float16* __restrict__ w1dp, const float* __restrict__ db1,
    const _Float16* __restrict__ w2dp, const float* __restrict__ db2,
    const float* __restrict__ dw3, const float* __restrict__ db3,
    float* __restrict__ out)
{
  __shared__ _Float16 d1[16][136];
  __shared__ float s2m[16][66];
  const int tid = threadIdx.x;
  const int wv  = tid >> 6;
  const int ln  = tid & 63;
  const int q   = ln >> 4;
  const int m   = ln & 15;
  const int n0  = blockIdx.x*16;      // grid = NN/16 = 1250 exact

  // stage 1: 8 cb over 4 waves -> 2 each
  floatx4 acc1[2];
  acc1[0] = (floatx4){0.f,0.f,0.f,0.f};
  acc1[1] = (floatx4){0.f,0.f,0.f,0.f};
  #pragma unroll
  for (int ks=0; ks<4; ++ks){
    half8 a = *(const half8*)(hh + (size_t)(n0+m)*HD + ks*32 + q*8);
    const _Float16* wb = w1dp + (size_t)(ks*8*64 + ln)*8;
    #pragma unroll
    for (int j=0; j<2; ++j){
      half8 b = *(const half8*)(wb + (size_t)(wv*2+j)*512);
      acc1[j] = __builtin_amdgcn_mfma_f32_16x16x32_f16(a, b, acc1[j], 0,0,0);
    }
  }
  #pragma unroll
  for (int j=0; j<2; ++j){
    const int c = (wv*2+j)*16 + m;
    const float bv = db1[c];
    #pragma unroll
    for (int r=0;r<4;++r)
      d1[q*4+r][c] = (_Float16)silu_f(acc1[j][r] + bv);
  }
  __syncthreads();

  // stage 2: 4 cb over 4 waves -> 1 each
  floatx4 acc2 = (floatx4){0.f,0.f,0.f,0.f};
  #pragma unroll
  for (int ks=0; ks<4; ++ks){
    half8 a = *(const half8*)&d1[m][ks*32 + q*8];
    const _Float16* wb = w2dp + (size_t)(ks*4*64 + ln)*8;
    half8 b = *(const half8*)(wb + (size_t)wv*512);
    acc2 = __builtin_amdgcn_mfma_f32_16x16x32_f16(a, b, acc2, 0,0,0);
  }
  {
    const int c = wv*16 + m;
    const float bv = db2[c];
    #pragma unroll
    for (int r=0;r<4;++r)
      s2m[q*4+r][c] = silu_f(acc2[r] + bv);
  }
  __syncthreads();

  // stage 3: 144 outputs over 256 threads
  if (tid < 144){
    int i = tid/9, oo = tid%9;
    float a = db3[oo];
    #pragma unroll 8
    for (int k=0;k<64;++k) a += s2m[i][k]*dw3[k*9+oo];
    out[(size_t)(n0+i)*9 + oo] = a;
  }
}

// ---------------- workspace layout (36,719,040 B) ----------------
constexpr size_t OFF_H    = 0;                         // 10,240,000
constexpr size_t OFF_HH   = 10240000;                  //  5,120,000
constexpr size_t OFF_UV   = 15360000;                  // 10,240,000
constexpr size_t OFF_S    = 25600000;                  //  5,120,000 (fp16)
constexpr size_t OFF_INVD = 30720000;                  //     80,000
constexpr size_t OFF_RS   = 30800000;                  //     80,064
constexpr size_t OFF_CUR  = 30880064;                  //     80,000
constexpr size_t OFF_REC  = 30960064;                  //  5,120,000 (int4/edge)
constexpr size_t OFF_W1P  = 36080064;                  //    393,216
constexpr size_t OFF_W2P  = 36473280;                  //    196,608
constexpr size_t OFF_DW1P = 36669888;                  //     32,768
constexpr size_t OFF_DW2P = 36702656;                  //     16,384
constexpr size_t WS_NEEDED= 36719040;

extern "C" void kernel_launch(void* const* d_in, const int* in_sizes, int n_in,
                              void* d_out, int out_size, void* d_ws, size_t ws_size,
                              hipStream_t stream)
{
  float* out = (float*)d_out;
  const int nout_blk = (out_size + 255)/256;

  static const int EXP_SIZES[17] = {280000,640000,960000,1792,128,16384,128,
                                    198912,768,98304,768,16384,128,8192,64,576,9};
  if (n_in != 17){
    sentinel_kernel<<<nout_blk, 256, 0, stream>>>(out, out_size, 2.0e7f + (float)n_in*1.0e3f);
    return;
  }
  for (int i = 0; i < 17; ++i){
    if (in_sizes[i] != EXP_SIZES[i]){
      int sz = in_sizes[i] < 99999 ? in_sizes[i] : 99999;
      sentinel_kernel<<<nout_blk, 256, 0, stream>>>(out, out_size,
          1.0e7f + (float)i*1.0e5f + (float)sz);
      return;
    }
  }
  if (ws_size < WS_NEEDED){
    sentinel_kernel<<<nout_blk, 256, 0, stream>>>(out, out_size, 1.0e6f);
    return;
  }

  const float* x       = (const float*)d_in[0];
  const int*   ei      = (const int*)  d_in[1];
  const float* eattr   = (const float*)d_in[2];
  const float* enc_w1  = (const float*)d_in[3];
  const float* enc_b1  = (const float*)d_in[4];
  const float* enc_w2  = (const float*)d_in[5];
  const float* enc_b2  = (const float*)d_in[6];
  const float* conv_w1 = (const float*)d_in[7];
  const float* conv_b1 = (const float*)d_in[8];
  const float* conv_w2 = (const float*)d_in[9];
  const float* conv_b2 = (const float*)d_in[10];
  const float* dec_w1  = (const float*)d_in[11];
  const float* dec_b1  = (const float*)d_in[12];
  const float* dec_w2  = (const float*)d_in[13];
  const float* dec_b2  = (const float*)d_in[14];
  const float* dec_w3  = (const float*)d_in[15];
  const float* dec_b3  = (const float*)d_in[16];

  char* ws = (char*)d_ws;
  float*    h     = (float*)   (ws + OFF_H);
  _Float16* hh    = (_Float16*)(ws + OFF_HH);
  _Float16* UV    = (_Float16*)(ws + OFF_UV);
  _Float16* S     = (_Float16*)(ws + OFF_S);
  float*    invd  = (float*)   (ws + OFF_INVD);
  int*      rstart= (int*)     (ws + OFF_RS);
  int*      cur   = (int*)     (ws + OFF_CUR);
  int4*     rec   = (int4*)    (ws + OFF_REC);
  _Float16* w1p   = (_Float16*)(ws + OFF_W1P);
  _Float16* w2p   = (_Float16*)(ws + OFF_W2P);
  _Float16* w1dp  = (_Float16*)(ws + OFF_DW1P);
  _Float16* w2dp  = (_Float16*)(ws + OFF_DW2P);

  hipMemsetAsync(cur, 0, (size_t)NN*sizeof(int), stream);

  pack_all_kernel<<<1248, 256, 0, stream>>>(conv_w1, conv_w2, dec_w1, dec_w2,
                                            w1p, w2p, w1dp, w2dp);
  count_kernel<<<EE/256, 256, 0, stream>>>(ei, cur);
  scan_kernel<<<1, 1024, 0, stream>>>(cur, rstart, invd);
  scatter_kernel<<<EE/256, 256, 0, stream>>>(ei, eattr, cur, rec);
  encoder_kernel<<<NN/16, 128, 0, stream>>>(x, enc_w1, enc_b1, enc_w2, enc_b2, h, hh);
  proj_kernel<<<NN/16, 256, 0, stream>>>(hh, w1p, conv_b1, UV);   // layer 0 proj
  for (int l=0; l<6; ++l){
    edge_agg_kernel<<<NN/4, 256, 0, stream>>>(UV, rstart, rec,
                                              conv_w1 + (size_t)l*33152 + 32768,
                                              invd, S);
    const int lp = (l < 5) ? l+1 : 0;   // dummy valid ptrs for last layer
    node_proj_kernel<<<NN/16, 256, 0, stream>>>(S, w2p + (size_t)l*16384,
                                                conv_b2 + (size_t)l*128, invd, h, hh,
                                                w1p + (size_t)lp*32768,
                                                conv_b1 + (size_t)lp*128,
                                                UV, (l < 5) ? 1 : 0);
  }
  decoder_kernel<<<NN/16, 256, 0, stream>>>(hh, w1dp, dec_b1, w2dp, dec_b2,
                                            dec_w3, dec_b3, out);
}

// Round 4
// 399.068 us; speedup vs baseline: 1.9186x; 1.1830x over previous
//
#include <hip/hip_runtime.h>
#include <hip/hip_bf16.h>

#define NN 20000
#define EE 320000
#define HD 128   // hidden

typedef _Float16 half8 __attribute__((ext_vector_type(8)));
typedef _Float16 half4 __attribute__((ext_vector_type(4)));
typedef _Float16 half2v __attribute__((ext_vector_type(2)));
typedef float floatx4 __attribute__((ext_vector_type(4)));
typedef float float2v __attribute__((ext_vector_type(2)));

// silu via HW rcp (1-ulp) instead of exact fp32 divide.
__device__ __forceinline__ float silu_f(float x){
  float e = __expf(-x);
  return x * __builtin_amdgcn_rcpf(1.f + e);
}

__device__ __forceinline__ bool ei_is64(const int* __restrict__ ei){
  return (ei[1] | ei[3] | ei[5] | ei[7]) == 0;
}
__device__ __forceinline__ int ei_src(const int* __restrict__ ei, int e, bool is64){
  return is64 ? ei[2*(size_t)e] : ei[e];
}
__device__ __forceinline__ int ei_dst(const int* __restrict__ ei, int e, bool is64){
  return is64 ? ei[2*(size_t)EE + 2*(size_t)e] : ei[EE + e];
}

__global__ __launch_bounds__(256) void sentinel_kernel(float* __restrict__ out, int n, float val){
  int i = blockIdx.x*256 + threadIdx.x;
  if (i < n) out[i] = val;
}

// ---------------- merged weight packing (w1p | w2p | dec) ----------------
__global__ __launch_bounds__(256) void pack_all_kernel(const float* __restrict__ cw1,
                                                       const float* __restrict__ cw2,
                                                       const float* __restrict__ dw1,
                                                       const float* __restrict__ dw2,
                                                       _Float16* __restrict__ w1p,
                                                       _Float16* __restrict__ w2p,
                                                       _Float16* __restrict__ w1dp,
                                                       _Float16* __restrict__ w2dp){
  int idx = blockIdx.x*256 + threadIdx.x;   // 1248 blocks = 319488 exact
  if (idx < 196608){
    int j   = idx & 7;
    int ln  = (idx >> 3) & 63;
    int rest= idx >> 9;
    int cb  = rest & 15;
    int rest2 = rest >> 4;
    int ks  = rest2 & 3;
    int l   = rest2 >> 2;
    int k = ks*32 + (ln>>4)*8 + j;
    int c = cb*16 + (ln&15);
    float v = (c < 128) ? cw1[(size_t)l*33152 + (size_t)k*128 + c]
                        : cw1[(size_t)l*33152 + (size_t)(128+k)*128 + (c-128)];
    w1p[idx] = (_Float16)v;
  } else if (idx < 294912){
    int t = idx - 196608;
    int j   = t & 7;
    int ln  = (t >> 3) & 63;
    int rest= t >> 9;
    int cb  = rest & 7;
    int rest2 = rest >> 3;
    int ks  = rest2 & 3;
    int l   = rest2 >> 2;
    int k = ks*32 + (ln>>4)*8 + j;
    int c = cb*16 + (ln&15);
    w2p[t] = (_Float16)cw2[(size_t)l*16384 + (size_t)k*128 + c];
  } else {
    int t2 = idx - 294912;
    if (t2 < 16384){
      int j = t2 & 7, ln = (t2>>3)&63, cb = (t2>>9)&7, ks = t2>>12;
      int k = ks*32 + (ln>>4)*8 + j;
      int c = cb*16 + (ln&15);
      w1dp[t2] = (_Float16)dw1[(size_t)k*128 + c];
    } else {
      int t = t2 - 16384;
      int j = t & 7, ln = (t>>3)&63, cb = (t>>9)&3, ks = t>>11;
      int k = ks*32 + (ln>>4)*8 + j;
      int c = cb*16 + (ln&15);
      w2dp[t] = (_Float16)dw2[(size_t)k*64 + c];
    }
  }
}

// ---------------- CSR build ----------------
__global__ __launch_bounds__(256) void count_kernel(const int* __restrict__ ei, int* __restrict__ cnt){
  int e = blockIdx.x*256 + threadIdx.x;   // EE/256 exact
  bool is64 = ei_is64(ei);
  atomicAdd(&cnt[ei_dst(ei, e, is64)], 1);
}

__global__ __launch_bounds__(1024) void scan_kernel(int* __restrict__ cntcur,
                                                    int* __restrict__ row_start,
                                                    float* __restrict__ invd){
  __shared__ int part[1024];
  const int t = threadIdx.x;
  const int base = t*20;
  int loc[20];
  int sum = 0;
  #pragma unroll
  for (int i=0;i<20;++i){
    int n = base+i;
    int v = (n < NN) ? cntcur[n] : 0;
    loc[i] = sum; sum += v;
  }
  part[t] = sum;
  __syncthreads();
  for (int off=1; off<1024; off<<=1){
    int v = (t >= off) ? part[t-off] : 0;
    __syncthreads();
    part[t] += v;
    __syncthreads();
  }
  int pre = (t > 0) ? part[t-1] : 0;
  #pragma unroll
  for (int i=0;i<20;++i){
    int n = base+i;
    if (n < NN){
      int rs = pre + loc[i];
      int deg = ((i<19)?loc[i+1]:sum) - loc[i];
      row_start[n] = rs;
      invd[n] = (deg > 0) ? 1.f/(float)deg : 0.f;
      cntcur[n] = rs;
    }
  }
  if (t == 1023) row_start[NN] = part[1023];
}

// scatter: one 16B record per edge: {ea0,ea1,ea2 (fp32 bits), src*256}.
__global__ __launch_bounds__(256) void scatter_kernel(const int* __restrict__ ei,
                                                      const float* __restrict__ eattr,
                                                      int* __restrict__ cur,
                                                      int4* __restrict__ rec){
  int e = blockIdx.x*256 + threadIdx.x;   // EE/256 exact
  bool is64 = ei_is64(ei);
  int s = ei_src(ei, e, is64);
  int d = ei_dst(ei, e, is64);
  int pos = atomicAdd(&cur[d], 1);
  int4 r;
  r.x = __float_as_int(eattr[(size_t)e*3+0]);
  r.y = __float_as_int(eattr[(size_t)e*3+1]);
  r.z = __float_as_int(eattr[(size_t)e*3+2]);
  r.w = s*256;   // pre-scaled UV row element-offset
  rec[pos] = r;
}

// ---------------- encoder: x(N,14) -> h(N,128) fp32 + hh fp16 ----------------
__global__ __launch_bounds__(128) void encoder_kernel(
    const float* __restrict__ x, const float* __restrict__ w1, const float* __restrict__ b1,
    const float* __restrict__ w2, const float* __restrict__ b2,
    float* __restrict__ h, _Float16* __restrict__ hh)
{
  __shared__ float xs[16][14];
  __shared__ float s1[16][128];
  const int n0 = blockIdx.x*16;
  const int tid = threadIdx.x;
  for (int idx=tid; idx<224; idx+=128){
    int i = idx/14, k = idx%14;
    xs[i][k] = x[(size_t)(n0+i)*14 + k];
  }
  __syncthreads();
  const int o = tid;
  float acc[16];
  float bv = b1[o];
  #pragma unroll
  for (int i=0;i<16;++i) acc[i] = bv;
  for (int k=0;k<14;++k){
    float w = w1[k*128+o];
    #pragma unroll
    for (int i=0;i<16;++i) acc[i] += xs[i][k]*w;
  }
  #pragma unroll
  for (int i=0;i<16;++i) s1[i][o] = silu_f(acc[i]);
  __syncthreads();
  float bv2 = b2[o];
  #pragma unroll
  for (int i=0;i<16;++i) acc[i] = bv2;
  for (int k=0;k<128;k+=4){
    float w0=w2[(k+0)*128+o], w1v=w2[(k+1)*128+o], w2v=w2[(k+2)*128+o], w3v=w2[(k+3)*128+o];
    #pragma unroll
    for (int i=0;i<16;++i){
      float4 sv = *(const float4*)&s1[i][k];
      acc[i] += sv.x*w0 + sv.y*w1v + sv.z*w2v + sv.w*w3v;
    }
  }
  #pragma unroll
  for (int i=0;i<16;++i){
    size_t off = (size_t)(n0+i)*HD + o;
    h[off] = acc[i];
    hh[off] = (_Float16)acc[i];
  }
}

// ---------------- proj (1250 blocks, 4 cb/wave): UV = [hh·W1d + b1 | hh·W1s] ----------------
__global__ __launch_bounds__(256) void proj_kernel(
    const _Float16* __restrict__ hh, const _Float16* __restrict__ w1p,
    const float* __restrict__ b1, _Float16* __restrict__ UV)
{
  const int tid = threadIdx.x;
  const int wv  = tid >> 6;
  const int ln  = tid & 63;
  const int q   = ln >> 4;
  const int m   = ln & 15;
  const int n0  = blockIdx.x*16;      // grid = NN/16 = 1250 exact

  floatx4 acc[4];
  #pragma unroll
  for (int j=0;j<4;++j) acc[j] = (floatx4){0.f,0.f,0.f,0.f};

  #pragma unroll
  for (int ks=0; ks<4; ++ks){
    half8 a = *(const half8*)(hh + (size_t)(n0+m)*HD + ks*32 + q*8);
    const _Float16* wb = w1p + (size_t)(ks*16*64 + ln)*8;
    #pragma unroll
    for (int j=0; j<4; ++j){
      half8 b = *(const half8*)(wb + (size_t)(wv*4+j)*512);
      acc[j] = __builtin_amdgcn_mfma_f32_16x16x32_f16(a, b, acc[j], 0,0,0);
    }
  }
  #pragma unroll
  for (int j=0; j<4; ++j){
    const int c = (wv*4+j)*16 + m;
    const float bias = (c < 128) ? b1[c] : 0.f;
    #pragma unroll
    for (int r=0;r<4;++r)
      UV[(size_t)(n0+q*4+r)*256 + c] = (_Float16)(acc[j][r] + bias);
  }
}

// ---------------- edge_agg: per-node mean of silu(U+V[src]+ea·We) ----------------
// r4: 4-deep software pipeline. Old loop had ONE outstanding gather per wave
// (depth-1 rolling prefetch) -> ~400-600cy L2/L3 gather latency exposed per
// edge. Quad structure issues 4 independent rec-load->gather chains per
// iteration (static indexing, 4 interleaved accumulators), raising per-SIMD
// outstanding gathers 8 -> 32 and deleting per-edge predication.
__device__ __forceinline__ float2v edge_contrib(int4 r, half2v v, float2v u,
                                                float2v wc0, float2v wc1, float2v wc2){
  float2v p = u;
  p += __int_as_float(r.x) * wc0;
  p += __int_as_float(r.y) * wc1;
  p += __int_as_float(r.z) * wc2;
  p[0] += (float)v[0];
  p[1] += (float)v[1];
  float2v s;
  s[0] = silu_f(p[0]);
  s[1] = silu_f(p[1]);
  return s;
}

__global__ __launch_bounds__(256) void edge_agg_kernel(
    const _Float16* __restrict__ UV, const int* __restrict__ row_start,
    const int4* __restrict__ rec,
    const float* __restrict__ w1e, const float* __restrict__ invd,
    _Float16* __restrict__ S)
{
  const int tid = threadIdx.x;
  const int wv  = __builtin_amdgcn_readfirstlane(tid >> 6);
  const int ln  = tid & 63;
  const int n   = blockIdx.x*4 + wv;   // grid NN/4 = 5000 exact
  const int c0  = ln*2;

  const float2v wc0 = *(const float2v*)(w1e +   0 + c0);
  const float2v wc1 = *(const float2v*)(w1e + 128 + c0);
  const float2v wc2 = *(const float2v*)(w1e + 256 + c0);

  half2v uvp = *(const half2v*)(UV + (size_t)n*256 + c0);
  float2v u; u[0] = (float)uvp[0]; u[1] = (float)uvp[1];

  const int rs = row_start[n], re = row_start[n+1];
  float2v a0 = {0.f,0.f}, a1 = {0.f,0.f}, a2 = {0.f,0.f}, a3 = {0.f,0.f};

  const int nq = (re - rs) >> 2;       // full quads
  int e = rs;
  for (int q = 0; q < nq; ++q, e += 4){
    const int4 r0 = rec[e+0];
    const int4 r1 = rec[e+1];
    const int4 r2 = rec[e+2];
    const int4 r3 = rec[e+3];
    const half2v v0 = *(const half2v*)(UV + (size_t)r0.w + 128 + c0);
    const half2v v1 = *(const half2v*)(UV + (size_t)r1.w + 128 + c0);
    const half2v v2 = *(const half2v*)(UV + (size_t)r2.w + 128 + c0);
    const half2v v3 = *(const half2v*)(UV + (size_t)r3.w + 128 + c0);
    a0 += edge_contrib(r0, v0, u, wc0, wc1, wc2);
    a1 += edge_contrib(r1, v1, u, wc0, wc1, wc2);
    a2 += edge_contrib(r2, v2, u, wc0, wc1, wc2);
    a3 += edge_contrib(r3, v3, u, wc0, wc1, wc2);
  }
  if (e < re){                          // remainder 1-3 edges (wave-uniform)
    const int e1 = (e+1 < re) ? e+1 : e;
    const int e2 = (e+2 < re) ? e+2 : e;
    const int4 r0 = rec[e];
    const int4 r1 = rec[e1];
    const int4 r2 = rec[e2];
    const half2v v0 = *(const half2v*)(UV + (size_t)r0.w + 128 + c0);
    const half2v v1 = *(const half2v*)(UV + (size_t)r1.w + 128 + c0);
    const half2v v2 = *(const half2v*)(UV + (size_t)r2.w + 128 + c0);
    a0 += edge_contrib(r0, v0, u, wc0, wc1, wc2);
    if (e+1 < re) a1 += edge_contrib(r1, v1, u, wc0, wc1, wc2);
    if (e+2 < re) a2 += edge_contrib(r2, v2, u, wc0, wc1, wc2);
  }
  float2v a = (a0 + a1) + (a2 + a3);
  const float iv = invd[n];
  half2v outv; outv[0] = (_Float16)(a[0]*iv); outv[1] = (_Float16)(a[1]*iv);
  *(half2v*)(S + (size_t)n*HD + c0) = outv;
}

// ---------------- node_proj (1250 blocks): h += S·W2 + gate·b2 ; hh ; fused proj(l+1) ----------------
__global__ __launch_bounds__(256) void node_proj_kernel(
    const _Float16* __restrict__ S, const _Float16* __restrict__ w2p,
    const float* __restrict__ b2, const float* __restrict__ invd,
    float* __restrict__ h, _Float16* __restrict__ hh,
    const _Float16* __restrict__ w1pn, const float* __restrict__ b1n,
    _Float16* __restrict__ UV, int do_proj)
{
  __shared__ _Float16 hl[16][136];
  const int tid = threadIdx.x;
  const int wv  = tid >> 6;
  const int ln  = tid & 63;
  const int q   = ln >> 4;
  const int m   = ln & 15;
  const int n0  = blockIdx.x*16;      // grid = NN/16 = 1250 exact

  floatx4 acc[2];
  acc[0] = (floatx4){0.f,0.f,0.f,0.f};
  acc[1] = (floatx4){0.f,0.f,0.f,0.f};
  #pragma unroll
  for (int ks=0; ks<4; ++ks){
    half8 a = *(const half8*)(S + (size_t)(n0+m)*HD + ks*32 + q*8);
    const _Float16* wb = w2p + (size_t)(ks*8*64 + ln)*8;
    #pragma unroll
    for (int j=0;j<2;++j){
      half8 b = *(const half8*)(wb + (size_t)(wv*2+j)*512);
      acc[j] = __builtin_amdgcn_mfma_f32_16x16x32_f16(a, b, acc[j], 0,0,0);
    }
  }
  float gate[4];
  #pragma unroll
  for (int r=0;r<4;++r) gate[r] = (invd[n0 + q*4 + r] > 0.f) ? 1.f : 0.f;
  #pragma unroll
  for (int j=0; j<2; ++j){
    const int c = (wv*2+j)*16 + m;
    const float bv = b2[c];
    #pragma unroll
    for (int r=0;r<4;++r){
      size_t off = (size_t)(n0+q*4+r)*HD + c;
      float hv = h[off] + acc[j][r] + gate[r]*bv;
      h[off] = hv;
      hh[off] = (_Float16)hv;
      hl[q*4+r][c] = (_Float16)hv;
    }
  }
  __syncthreads();
  if (do_proj){
    floatx4 acc2[4];
    #pragma unroll
    for (int j=0;j<4;++j) acc2[j] = (floatx4){0.f,0.f,0.f,0.f};
    #pragma unroll
    for (int ks=0; ks<4; ++ks){
      half8 a = *(const half8*)&hl[m][ks*32 + q*8];
      const _Float16* wb = w1pn + (size_t)(ks*16*64 + ln)*8;
      #pragma unroll
      for (int j=0; j<4; ++j){
        half8 b = *(const half8*)(wb + (size_t)(wv*4+j)*512);
        acc2[j] = __builtin_amdgcn_mfma_f32_16x16x32_f16(a, b, acc2[j], 0,0,0);
      }
    }
    #pragma unroll
    for (int j=0; j<4; ++j){
      const int c = (wv*4+j)*16 + m;
      const float bias = (c < 128) ? b1n[c] : 0.f;
      #pragma unroll
      for (int r=0;r<4;++r)
        UV[(size_t)(n0+q*4+r)*256 + c] = (_Float16)(acc2[j][r] + bias);
    }
  }
}

// ---------------- decoder (1250 blocks): hh -> out(N,9) ----------------
__global__ __launch_bounds__(256) void decoder_kernel(
    const _Float16* __restrict__ hh,
    const _Float16* __restrict__ w1dp, const float* __restrict__ db1,
    const _Float16* __restrict__ w2dp, const float* __restrict__ db2,
    const float* __restrict__ dw3, const float* __restrict__ db3,
    float* __restrict__ out)
{
  __shared__ _Float16 d1[16][136];
  __shared__ float s2m[16][66];
  const int tid = threadIdx.x;
  const int wv  = tid >> 6;
  const int ln  = tid & 63;
  const int q   = ln >> 4;
  const int m   = ln & 15;
  const int n0  = blockIdx.x*16;      // grid = NN/16 = 1250 exact

  // stage 1: 8 cb over 4 waves -> 2 each
  floatx4 acc1[2];
  acc1[0] = (floatx4){0.f,0.f,0.f,0.f};
  acc1[1] = (floatx4){0.f,0.f,0.f,0.f};
  #pragma unroll
  for (int ks=0; ks<4; ++ks){
    half8 a = *(const half8*)(hh + (size_t)(n0+m)*HD + ks*32 + q*8);
    const _Float16* wb = w1dp + (size_t)(ks*8*64 + ln)*8;
    #pragma unroll
    for (int j=0; j<2; ++j){
      half8 b = *(const half8*)(wb + (size_t)(wv*2+j)*512);
      acc1[j] = __builtin_amdgcn_mfma_f32_16x16x32_f16(a, b, acc1[j], 0,0,0);
    }
  }
  #pragma unroll
  for (int j=0; j<2; ++j){
    const int c = (wv*2+j)*16 + m;
    const float bv = db1[c];
    #pragma unroll
    for (int r=0;r<4;++r)
      d1[q*4+r][c] = (_Float16)silu_f(acc1[j][r] + bv);
  }
  __syncthreads();

  // stage 2: 4 cb over 4 waves -> 1 each
  floatx4 acc2 = (floatx4){0.f,0.f,0.f,0.f};
  #pragma unroll
  for (int ks=0; ks<4; ++ks){
    half8 a = *(const half8*)&d1[m][ks*32 + q*8];
    const _Float16* wb = w2dp + (size_t)(ks*4*64 + ln)*8;
    half8 b = *(const half8*)(wb + (size_t)wv*512);
    acc2 = __builtin_amdgcn_mfma_f32_16x16x32_f16(a, b, acc2, 0,0,0);
  }
  {
    const int c = wv*16 + m;
    const float bv = db2[c];
    #pragma unroll
    for (int r=0;r<4;++r)
      s2m[q*4+r][c] = silu_f(acc2[r] + bv);
  }
  __syncthreads();

  // stage 3: 144 outputs over 256 threads
  if (tid < 144){
    int i = tid/9, oo = tid%9;
    float a = db3[oo];
    #pragma unroll 8
    for (int k=0;k<64;++k) a += s2m[i][k]*dw3[k*9+oo];
    out[(size_t)(n0+i)*9 + oo] = a;
  }
}

// ---------------- workspace layout (36,719,040 B) ----------------
constexpr size_t OFF_H    = 0;                         // 10,240,000
constexpr size_t OFF_HH   = 10240000;                  //  5,120,000
constexpr size_t OFF_UV   = 15360000;                  // 10,240,000
constexpr size_t OFF_S    = 25600000;                  //  5,120,000 (fp16)
constexpr size_t OFF_INVD = 30720000;                  //     80,000
constexpr size_t OFF_RS   = 30800000;                  //     80,064
constexpr size_t OFF_CUR  = 30880064;                  //     80,000
constexpr size_t OFF_REC  = 30960064;                  //  5,120,000 (int4/edge)
constexpr size_t OFF_W1P  = 36080064;                  //    393,216
constexpr size_t OFF_W2P  = 36473280;                  //    196,608
constexpr size_t OFF_DW1P = 36669888;                  //     32,768
constexpr size_t OFF_DW2P = 36702656;                  //     16,384
constexpr size_t WS_NEEDED= 36719040;

extern "C" void kernel_launch(void* const* d_in, const int* in_sizes, int n_in,
                              void* d_out, int out_size, void* d_ws, size_t ws_size,
                              hipStream_t stream)
{
  float* out = (float*)d_out;
  const int nout_blk = (out_size + 255)/256;

  static const int EXP_SIZES[17] = {280000,640000,960000,1792,128,16384,128,
                                    198912,768,98304,768,16384,128,8192,64,576,9};
  if (n_in != 17){
    sentinel_kernel<<<nout_blk, 256, 0, stream>>>(out, out_size, 2.0e7f + (float)n_in*1.0e3f);
    return;
  }
  for (int i = 0; i < 17; ++i){
    if (in_sizes[i] != EXP_SIZES[i]){
      int sz = in_sizes[i] < 99999 ? in_sizes[i] : 99999;
      sentinel_kernel<<<nout_blk, 256, 0, stream>>>(out, out_size,
          1.0e7f + (float)i*1.0e5f + (float)sz);
      return;
    }
  }
  if (ws_size < WS_NEEDED){
    sentinel_kernel<<<nout_blk, 256, 0, stream>>>(out, out_size, 1.0e6f);
    return;
  }

  const float* x       = (const float*)d_in[0];
  const int*   ei      = (const int*)  d_in[1];
  const float* eattr   = (const float*)d_in[2];
  const float* enc_w1  = (const float*)d_in[3];
  const float* enc_b1  = (const float*)d_in[4];
  const float* enc_w2  = (const float*)d_in[5];
  const float* enc_b2  = (const float*)d_in[6];
  const float* conv_w1 = (const float*)d_in[7];
  const float* conv_b1 = (const float*)d_in[8];
  const float* conv_w2 = (const float*)d_in[9];
  const float* conv_b2 = (const float*)d_in[10];
  const float* dec_w1  = (const float*)d_in[11];
  const float* dec_b1  = (const float*)d_in[12];
  const float* dec_w2  = (const float*)d_in[13];
  const float* dec_b2  = (const float*)d_in[14];
  const float* dec_w3  = (const float*)d_in[15];
  const float* dec_b3  = (const float*)d_in[16];

  char* ws = (char*)d_ws;
  float*    h     = (float*)   (ws + OFF_H);
  _Float16* hh    = (_Float16*)(ws + OFF_HH);
  _Float16* UV    = (_Float16*)(ws + OFF_UV);
  _Float16* S     = (_Float16*)(ws + OFF_S);
  float*    invd  = (float*)   (ws + OFF_INVD);
  int*      rstart= (int*)     (ws + OFF_RS);
  int*      cur   = (int*)     (ws + OFF_CUR);
  int4*     rec   = (int4*)    (ws + OFF_REC);
  _Float16* w1p   = (_Float16*)(ws + OFF_W1P);
  _Float16* w2p   = (_Float16*)(ws + OFF_W2P);
  _Float16* w1dp  = (_Float16*)(ws + OFF_DW1P);
  _Float16* w2dp  = (_Float16*)(ws + OFF_DW2P);

  hipMemsetAsync(cur, 0, (size_t)NN*sizeof(int), stream);

  pack_all_kernel<<<1248, 256, 0, stream>>>(conv_w1, conv_w2, dec_w1, dec_w2,
                                            w1p, w2p, w1dp, w2dp);
  count_kernel<<<EE/256, 256, 0, stream>>>(ei, cur);
  scan_kernel<<<1, 1024, 0, stream>>>(cur, rstart, invd);
  scatter_kernel<<<EE/256, 256, 0, stream>>>(ei, eattr, cur, rec);
  encoder_kernel<<<NN/16, 128, 0, stream>>>(x, enc_w1, enc_b1, enc_w2, enc_b2, h, hh);
  proj_kernel<<<NN/16, 256, 0, stream>>>(hh, w1p, conv_b1, UV);   // layer 0 proj
  for (int l=0; l<6; ++l){
    edge_agg_kernel<<<NN/4, 256, 0, stream>>>(UV, rstart, rec,
                                              conv_w1 + (size_t)l*33152 + 32768,
                                              invd, S);
    const int lp = (l < 5) ? l+1 : 0;   // dummy valid ptrs for last layer
    node_proj_kernel<<<NN/16, 256, 0, stream>>>(S, w2p + (size_t)l*16384,
                                                conv_b2 + (size_t)l*128, invd, h, hh,
                                                w1p + (size_t)lp*32768,
                                                conv_b1 + (size_t)lp*128,
                                                UV, (l < 5) ? 1 : 0);
  }
  decoder_kernel<<<NN/16, 256, 0, stream>>>(hh, w1dp, dec_b1, w2dp, dec_b2,
                                            dec_w3, dec_b3, out);
}